// Round 8
// baseline (1092.438 us; speedup 1.0000x reference)
//
#include <hip/hip_runtime.h>

// Viterbi decode (LinearCRF): features [B,S,L] f32, transitions [L,L] f32 -> best_path [B,S] int32
// B=512, S=1024, L=64. One wave per FOUR batch elements; lane = tag j.
// The 1023-step recurrence is serial per sequence; a lone wave exposes every issue
// bubble + ds_read latency (r7: 551 cyc/step, VALUBusy 13%). Interleaving 4
// independent sequences per wave fills the bubbles: per-iteration wall =
// max(4x issue, 1x chain) => ~130-175 cyc/step effective.
constexpr int Bn = 512;
constexpr int Sn = 1024;
constexpr int Ln = 64;
constexpr int NSEQ = 4;

// ---- wave64 max reduction via DPP ----
#define DPPMAX(ctrl)                                                          \
  {                                                                           \
    int _xi = __float_as_int(x);                                              \
    int _yi = __builtin_amdgcn_update_dpp(_xi, _xi, ctrl, 0xf, 0xf, false);   \
    x = fmaxf(x, __int_as_float(_yi));                                        \
  }

__device__ __forceinline__ float wave_max64(float x) {
  DPPMAX(0x121)  // row_ror:1
  DPPMAX(0x122)  // row_ror:2
  DPPMAX(0x124)  // row_ror:4
  DPPMAX(0x128)  // row_ror:8
  DPPMAX(0x142)  // row_bcast15
  DPPMAX(0x143)  // row_bcast31 -> lane 63 holds wave max
  return __int_as_float(__builtin_amdgcn_readlane(__float_as_int(x), 63));
}

__device__ __forceinline__ float rdlane(float v, int lane) {
  return __int_as_float(__builtin_amdgcn_readlane(__float_as_int(v), lane));
}

// One Viterbi step for all 4 sequences, branch-free except the never-taken rare
// fixup. Exact arithmetic: scores rnd(fv_i + T[i][j]); selection strict-> in
// ascending candidate index == np.argmax first-index rule; candidate set provably
// supersets column winners (margin Dspan+0.01 >> fp slack). k<4 duplicates
// candidates (tie-safe, r5-verified). s0 uses rdlane(fv,i0) (r6 bug: used M).
// SH_ = (T_)&3 as a literal; CLOSE_ = 1 iff SH_==3 (coal word completes).
#define STEP4(T_, S_, SH_, CLOSE_, DO_PREF, PREF_T)                              \
  do {                                                                           \
    const int t_ = (T_);                                                         \
    float fvold_[NSEQ], featc_[NSEQ];                                            \
    unsigned long long cm_[NSEQ];                                                \
    int k_[NSEQ];                                                                \
    int anyrare_ = 0;                                                            \
    _Pragma("unroll")                                                            \
    for (int q = 0; q < NSEQ; ++q) {                                             \
      featc_[q] = pf[q][(S_)];                                                   \
      if (DO_PREF) pf[q][(S_)] = fb[q][(size_t)(PREF_T) * Ln];                   \
      const float fo_ = fv[q];                                                   \
      fvold_[q] = fo_;                                                           \
      const float M = wave_max64(fo_);                                           \
      const unsigned long long cm = __ballot(fo_ >= M - DpE);                    \
      cm_[q] = cm;                                                               \
      const int k = __popcll(cm);                                                \
      k_[q] = k;                                                                 \
      anyrare_ |= (int)(k > 4);                                                  \
      const int i0 = __ffsll((long long)cm) - 1;                                 \
      const unsigned long long m1 = cm & (cm - 1);                               \
      const unsigned long long m2 = m1 & (m1 - 1);                               \
      const unsigned long long m3 = m2 & (m2 - 1);                               \
      const int i1 = (k > 1) ? (__ffsll((long long)m1) - 1) : i0;                \
      const int i2 = (k > 2) ? (__ffsll((long long)m2) - 1) : i1;                \
      const int i3 = (k > 3) ? (__ffsll((long long)m3) - 1) : i1;                \
      const float s0 = rdlane(fo_, i0) + sT[i0 * Ln + j];                        \
      const float s1 = rdlane(fo_, i1) + sT[i1 * Ln + j];                        \
      const float s2 = rdlane(fo_, i2) + sT[i2 * Ln + j];                        \
      const float s3 = rdlane(fo_, i3) + sT[i3 * Ln + j];                        \
      const bool tkA = s1 > s0;                                                  \
      const float vA = tkA ? s1 : s0;                                            \
      const int xA = tkA ? i1 : i0;                                              \
      const bool tkB = s3 > s2;                                                  \
      const float vB = tkB ? s3 : s2;                                            \
      const int xB = tkB ? i3 : i2;                                              \
      const bool tkF = (k > 2) && (vB > vA);                                     \
      const float best = tkF ? vB : vA;                                          \
      const int bx = tkF ? xB : xA;                                              \
      fv[q] = featc_[q] + best;                                                  \
      bpq[q][(size_t)(t_ - 1) * Ln] = (unsigned char)bx;                         \
      const unsigned cv = (k == 1) ? (unsigned)i0 : 0xFFu;                       \
      cw[q] |= (cv << (8 * (SH_)));                                              \
    }                                                                            \
    if (__builtin_expect(anyrare_, 0)) {                                         \
      _Pragma("unroll")                                                          \
      for (int q = 0; q < NSEQ; ++q) {                                           \
        if (k_[q] > 4) {                                                         \
          unsigned long long m = cm_[q];                                         \
          int i = __ffsll((long long)m) - 1;                                     \
          m &= m - 1;                                                            \
          float best = rdlane(fvold_[q], i) + sT[i * Ln + j];                    \
          int bx = i;                                                            \
          while (m) {                                                            \
            i = __ffsll((long long)m) - 1;                                       \
            m &= m - 1;                                                          \
            const float s = rdlane(fvold_[q], i) + sT[i * Ln + j];               \
            const bool tk = s > best;                                            \
            best = tk ? s : best;                                                \
            bx = tk ? i : bx;                                                    \
          }                                                                      \
          fv[q] = featc_[q] + best;                                              \
          bpq[q][(size_t)(t_ - 1) * Ln] = (unsigned char)bx;                     \
        }                                                                        \
      }                                                                          \
    }                                                                            \
    if (CLOSE_) {                                                                \
      if (j == 0) {                                                              \
        _Pragma("unroll")                                                        \
        for (int q = 0; q < NSEQ; ++q) coalq[q][t_ >> 2] = cw[q];                \
      }                                                                          \
      _Pragma("unroll")                                                          \
      for (int q = 0; q < NSEQ; ++q) cw[q] = 0;                                  \
    }                                                                            \
  } while (0)

__global__ __launch_bounds__(64) void crf_forward4(
    const float* __restrict__ feat,       // [B][S][L]
    const float* __restrict__ Tm,         // [L][L]
    unsigned char* __restrict__ bp,       // [B][S-1][L] backpointers (all steps)
    unsigned* __restrict__ coal,          // [B][S/4 words]: per-step istar or 0xFF bytes
    int* __restrict__ last_tag)           // [B]
{
  const int b0 = blockIdx.x * NSEQ;
  const int j = threadIdx.x;  // tag index 0..63

  __shared__ __align__(16) float sT[Ln * Ln];  // transitions row-major

  // stage T, tracking global span
  float tmx = -1e30f, tmn = 1e30f;
#pragma unroll 8
  for (int i = 0; i < Ln; ++i) {
    const float v = Tm[i * Ln + j];
    sT[i * Ln + j] = v;
    tmx = fmaxf(tmx, v);
    tmn = fminf(tmn, v);
  }
  __syncthreads();
#pragma unroll
  for (int off = 32; off >= 1; off >>= 1) {
    tmx = fmaxf(tmx, __shfl_xor(tmx, off));
    tmn = fminf(tmn, __shfl_xor(tmn, off));
  }
  // fixed margin: Dspan + 0.01 covers all fp rounding (|fv| <= ~6e3 -> 2ulp ~ 1e-3)
  const float DpE = (tmx - tmn) + 0.01f;

  const float* fb[NSEQ];
  unsigned char* bpq[NSEQ];
  unsigned* coalq[NSEQ];
  float fv[NSEQ];
  float pf[NSEQ][4];
  unsigned cw[NSEQ];
#pragma unroll
  for (int q = 0; q < NSEQ; ++q) {
    fb[q] = feat + ((size_t)(b0 + q) * Sn) * Ln + j;
    bpq[q] = bp + ((size_t)(b0 + q) * (Sn - 1)) * Ln + j;
    coalq[q] = coal + (size_t)(b0 + q) * (Sn / 4);
    fv[q] = fb[q][0];
    cw[q] = 0;
#pragma unroll
    for (int s = 0; s < 4; ++s) pf[q][s] = fb[q][(size_t)(1 + s) * Ln];
  }

  // ---- main loop: t = 1 .. 1016 (254 blocks of 4); prefetch t+4 <= 1020 ----
  for (int tb = 1; tb <= Sn - 11; tb += 4) {
    STEP4(tb + 0, 0, 1, 0, true, tb + 4);
    STEP4(tb + 1, 1, 2, 0, true, tb + 5);
    STEP4(tb + 2, 2, 3, 1, true, tb + 6);
    STEP4(tb + 3, 3, 0, 0, true, tb + 7);
  }
  // After main loop: pf[q][s] = feature[1017 + s].

  // ---- tail A: t = 1017..1020; refill slots 0..2 with features 1021..1023 ----
  STEP4(1017, 0, 1, 0, true, 1021);
  STEP4(1018, 1, 2, 0, true, 1022);
  STEP4(1019, 2, 3, 1, true, 1023);
  STEP4(1020, 3, 0, 0, false, 0);

  // ---- tail B: t = 1021..1023 ----
  STEP4(1021, 0, 1, 0, false, 0);
  STEP4(1022, 1, 2, 0, false, 0);
  STEP4(1023, 2, 3, 1, false, 0);

  // last_tag = first-index argmax of final forward_var, per sequence
  int lt[NSEQ];
#pragma unroll
  for (int q = 0; q < NSEQ; ++q) {
    const float Mf = wave_max64(fv[q]);
    const unsigned long long mk = __ballot(fv[q] == Mf);
    lt[q] = __ffsll((long long)mk) - 1;
  }
  if (j == 0) {
#pragma unroll
    for (int q = 0; q < NSEQ; ++q) last_tag[b0 + q] = lt[q];
  }
}

__global__ __launch_bounds__(256) void crf_backtrace(
    const unsigned char* __restrict__ bp, const unsigned char* __restrict__ coal,
    const int* __restrict__ last_tag, int* __restrict__ out)
{
  const int gid = blockIdx.x * blockDim.x + threadIdx.x;
  if (gid >= Bn * Sn) return;
  const int b = gid >> 10;       // / Sn
  const int t = gid & (Sn - 1);  // % Sn

  const unsigned char* cb = coal + (size_t)b * Sn;
  int tag = -1;
  int u = t;
  // walk forward to the nearest chain break (coalesced k==1 step or sequence end)
  while (u < Sn - 1) {
    const unsigned char c = cb[u + 1];
    if (c != 0xFF) { tag = c; break; }  // path[u] = istar of step u+1
    ++u;
  }
  if (u == Sn - 1) tag = last_tag[b];
  // walk back through non-coalesced steps applying stored backpointers
  const unsigned char* bpb = bp + (size_t)b * (Sn - 1) * Ln;
  for (; u > t; --u) tag = bpb[(size_t)(u - 1) * Ln + tag];
  out[gid] = tag;
}

extern "C" void kernel_launch(void* const* d_in, const int* in_sizes, int n_in,
                              void* d_out, int out_size, void* d_ws, size_t ws_size,
                              hipStream_t stream) {
  const float* feat = (const float*)d_in[0];
  const float* Tm = (const float*)d_in[1];

  // workspace layout: bp | coal | last_tag   (~34 MB total)
  unsigned char* bp = (unsigned char*)d_ws;
  const size_t bp_sz = (size_t)Bn * (Sn - 1) * Ln;  // 33,521,664 (word-aligned)
  unsigned char* coal = bp + bp_sz;
  const size_t coal_sz = (size_t)Bn * Sn;           // 524,288
  int* last_tag = (int*)(coal + coal_sz);

  int* out = (int*)d_out;

  crf_forward4<<<Bn / NSEQ, 64, 0, stream>>>(feat, Tm, bp, (unsigned*)coal, last_tag);
  const int total = Bn * Sn;
  crf_backtrace<<<(total + 255) / 256, 256, 0, stream>>>(bp, coal, last_tag, out);
}

// Round 9
// 1063.471 us; speedup vs baseline: 1.0272x; 1.0272x over previous
//
#include <hip/hip_runtime.h>

// Viterbi decode (LinearCRF): features [B,S,L] f32, transitions [L,L] f32 -> best_path [B,S] int32
// B=512, S=1024, L=64. One wave per FOUR batch elements; lane = tag j.
// Waves issue IN ORDER: intra-wave overlap of the 4 sequences must be compiled in.
// r8 failed because the compiler (targeting default occupancy) serialized the 4
// bodies to save registers. This version: __launch_bounds__(64,1) for a full VGPR
// budget + phase-interleaved source so consecutive dependent ops are >=4 apart.
constexpr int Bn = 512;
constexpr int Sn = 1024;
constexpr int Ln = 64;
constexpr int NSEQ = 4;

// one DPP max level on one variable
#define DPP1(v, ctrl)                                                            \
  {                                                                              \
    int _xi = __float_as_int(v);                                                 \
    int _yi = __builtin_amdgcn_update_dpp(_xi, _xi, ctrl, 0xf, 0xf, false);      \
    v = fmaxf(v, __int_as_float(_yi));                                           \
  }

__device__ __forceinline__ float wave_max64(float x) {
  DPP1(x, 0x121) DPP1(x, 0x122) DPP1(x, 0x124) DPP1(x, 0x128)
  DPP1(x, 0x142) DPP1(x, 0x143)
  return __int_as_float(__builtin_amdgcn_readlane(__float_as_int(x), 63));
}

__device__ __forceinline__ float rdlane(float v, int lane) {
  return __int_as_float(__builtin_amdgcn_readlane(__float_as_int(v), lane));
}

// One Viterbi step for 4 sequences, PHASE-interleaved. Exact arithmetic: scores
// rnd(fv_i + T[i][j]); selection strict-> ascending candidate index == np.argmax
// first-index rule; candidate set supersets column winners (margin Dspan+0.01).
// k<4 duplicates candidates (tie-safe); s0 uses rdlane(fv,i0) (r6 lesson).
#define STEP4(T_, S_, SH_, CLOSE_, DO_PREF, PREF_T)                              \
  do {                                                                           \
    const int t_ = (T_);                                                         \
    /* P0: consume feature, issue prefetch (latency hidden behind whole step) */ \
    float featc_[NSEQ];                                                          \
    _Pragma("unroll")                                                            \
    for (int q = 0; q < NSEQ; ++q) {                                             \
      featc_[q] = pf[q][(S_)];                                                   \
      if (DO_PREF) pf[q][(S_)] = fb[q][(size_t)(PREF_T) * Ln];                   \
    }                                                                            \
    /* P1: 4 DPP max trees, level-interleaved (4 independent ops per level) */   \
    float m0_ = fv[0], m1_ = fv[1], m2_ = fv[2], m3_ = fv[3];                    \
    DPP1(m0_, 0x121) DPP1(m1_, 0x121) DPP1(m2_, 0x121) DPP1(m3_, 0x121)         \
    DPP1(m0_, 0x122) DPP1(m1_, 0x122) DPP1(m2_, 0x122) DPP1(m3_, 0x122)         \
    DPP1(m0_, 0x124) DPP1(m1_, 0x124) DPP1(m2_, 0x124) DPP1(m3_, 0x124)         \
    DPP1(m0_, 0x128) DPP1(m1_, 0x128) DPP1(m2_, 0x128) DPP1(m3_, 0x128)         \
    DPP1(m0_, 0x142) DPP1(m1_, 0x142) DPP1(m2_, 0x142) DPP1(m3_, 0x142)         \
    DPP1(m0_, 0x143) DPP1(m1_, 0x143) DPP1(m2_, 0x143) DPP1(m3_, 0x143)         \
    float M_[NSEQ];                                                              \
    M_[0] = __int_as_float(__builtin_amdgcn_readlane(__float_as_int(m0_), 63));  \
    M_[1] = __int_as_float(__builtin_amdgcn_readlane(__float_as_int(m1_), 63));  \
    M_[2] = __int_as_float(__builtin_amdgcn_readlane(__float_as_int(m2_), 63));  \
    M_[3] = __int_as_float(__builtin_amdgcn_readlane(__float_as_int(m3_), 63));  \
    /* P2: 4 ballots (independent) */                                            \
    unsigned long long cm_[NSEQ];                                                \
    _Pragma("unroll")                                                            \
    for (int q = 0; q < NSEQ; ++q) cm_[q] = __ballot(fv[q] >= M_[q] - DpE);      \
    /* P3: SALU candidate extraction (wave-uniform, scalar pipe) */              \
    int k_[NSEQ], i0_[NSEQ], i1_[NSEQ], i2_[NSEQ], i3_[NSEQ];                    \
    int anyrare_ = 0;                                                            \
    _Pragma("unroll")                                                            \
    for (int q = 0; q < NSEQ; ++q) {                                             \
      const unsigned long long cm = cm_[q];                                      \
      const int k = __popcll(cm);                                                \
      k_[q] = k;                                                                 \
      anyrare_ |= (int)(k > 4);                                                  \
      const int i0 = __ffsll((long long)cm) - 1;                                 \
      const unsigned long long m1 = cm & (cm - 1);                               \
      const unsigned long long m2 = m1 & (m1 - 1);                               \
      const unsigned long long m3 = m2 & (m2 - 1);                               \
      i0_[q] = i0;                                                               \
      i1_[q] = (k > 1) ? (__ffsll((long long)m1) - 1) : i0;                      \
      i2_[q] = (k > 2) ? (__ffsll((long long)m2) - 1) : i1_[q];                  \
      i3_[q] = (k > 3) ? (__ffsll((long long)m3) - 1) : i1_[q];                  \
    }                                                                            \
    /* P4: issue ALL 16 ds_reads back-to-back */                                 \
    float t0_[NSEQ], t1_[NSEQ], t2_[NSEQ], t3_[NSEQ];                            \
    _Pragma("unroll")                                                            \
    for (int q = 0; q < NSEQ; ++q) {                                             \
      t0_[q] = sT[i0_[q] * Ln + j];                                              \
      t1_[q] = sT[i1_[q] * Ln + j];                                              \
      t2_[q] = sT[i2_[q] * Ln + j];                                              \
      t3_[q] = sT[i3_[q] * Ln + j];                                              \
    }                                                                            \
    /* P5: 16 readlanes (VALU) issue while LDS reads are in flight */            \
    float r0_[NSEQ], r1_[NSEQ], r2_[NSEQ], r3_[NSEQ];                            \
    _Pragma("unroll")                                                            \
    for (int q = 0; q < NSEQ; ++q) {                                             \
      r0_[q] = rdlane(fv[q], i0_[q]);                                            \
      r1_[q] = rdlane(fv[q], i1_[q]);                                            \
      r2_[q] = rdlane(fv[q], i2_[q]);                                            \
      r3_[q] = rdlane(fv[q], i3_[q]);                                            \
    }                                                                            \
    /* P6: score trees + select + update + stores */                             \
    _Pragma("unroll")                                                            \
    for (int q = 0; q < NSEQ; ++q) {                                             \
      const float s0 = r0_[q] + t0_[q];                                          \
      const float s1 = r1_[q] + t1_[q];                                          \
      const float s2 = r2_[q] + t2_[q];                                          \
      const float s3 = r3_[q] + t3_[q];                                          \
      const bool tkA = s1 > s0;                                                  \
      const float vA = tkA ? s1 : s0;                                            \
      const int xA = tkA ? i1_[q] : i0_[q];                                      \
      const bool tkB = s3 > s2;                                                  \
      const float vB = tkB ? s3 : s2;                                            \
      const int xB = tkB ? i3_[q] : i2_[q];                                      \
      const bool tkF = (k_[q] > 2) && (vB > vA);                                 \
      const float best = tkF ? vB : vA;                                          \
      const int bx = tkF ? xB : xA;                                              \
      fvold_[q] = fv[q];                                                         \
      fv[q] = featc_[q] + best;                                                  \
      bpq[q][(size_t)(t_ - 1) * Ln] = (unsigned char)bx;                         \
      const unsigned cv = (k_[q] == 1) ? (unsigned)i0_[q] : 0xFFu;               \
      cw[q] |= (cv << (8 * (SH_)));                                              \
    }                                                                            \
    if (__builtin_expect(anyrare_, 0)) {                                         \
      _Pragma("unroll")                                                          \
      for (int q = 0; q < NSEQ; ++q) {                                           \
        if (k_[q] > 4) {                                                         \
          unsigned long long m = cm_[q];                                         \
          int i = __ffsll((long long)m) - 1;                                     \
          m &= m - 1;                                                            \
          float best = rdlane(fvold_[q], i) + sT[i * Ln + j];                    \
          int bx = i;                                                            \
          while (m) {                                                            \
            i = __ffsll((long long)m) - 1;                                       \
            m &= m - 1;                                                          \
            const float s = rdlane(fvold_[q], i) + sT[i * Ln + j];               \
            const bool tk = s > best;                                            \
            best = tk ? s : best;                                                \
            bx = tk ? i : bx;                                                    \
          }                                                                      \
          fv[q] = featc_[q] + best;                                              \
          bpq[q][(size_t)(t_ - 1) * Ln] = (unsigned char)bx;                     \
        }                                                                        \
      }                                                                          \
    }                                                                            \
    if (CLOSE_) {                                                                \
      if (j == 0) {                                                              \
        _Pragma("unroll")                                                        \
        for (int q = 0; q < NSEQ; ++q) coalq[q][t_ >> 2] = cw[q];                \
      }                                                                          \
      _Pragma("unroll")                                                          \
      for (int q = 0; q < NSEQ; ++q) cw[q] = 0;                                  \
    }                                                                            \
  } while (0)

__global__ __launch_bounds__(64, 1) void crf_forward4(
    const float* __restrict__ feat,       // [B][S][L]
    const float* __restrict__ Tm,         // [L][L]
    unsigned char* __restrict__ bp,       // [B][S-1][L] backpointers (all steps)
    unsigned* __restrict__ coal,          // [B][S/4 words]: per-step istar or 0xFF bytes
    int* __restrict__ last_tag)           // [B]
{
  const int b0 = blockIdx.x * NSEQ;
  const int j = threadIdx.x;  // tag index 0..63

  __shared__ __align__(16) float sT[Ln * Ln];  // transitions row-major

  // stage T, tracking global span
  float tmx = -1e30f, tmn = 1e30f;
#pragma unroll 8
  for (int i = 0; i < Ln; ++i) {
    const float v = Tm[i * Ln + j];
    sT[i * Ln + j] = v;
    tmx = fmaxf(tmx, v);
    tmn = fminf(tmn, v);
  }
  __syncthreads();
#pragma unroll
  for (int off = 32; off >= 1; off >>= 1) {
    tmx = fmaxf(tmx, __shfl_xor(tmx, off));
    tmn = fminf(tmn, __shfl_xor(tmn, off));
  }
  // fixed margin: Dspan + 0.01 covers all fp rounding (|fv| <= ~6e3 -> 2ulp ~ 1e-3)
  const float DpE = (tmx - tmn) + 0.01f;

  const float* fb[NSEQ];
  unsigned char* bpq[NSEQ];
  unsigned* coalq[NSEQ];
  float fv[NSEQ];
  float fvold_[NSEQ];
  float pf[NSEQ][4];
  unsigned cw[NSEQ];
#pragma unroll
  for (int q = 0; q < NSEQ; ++q) {
    fb[q] = feat + ((size_t)(b0 + q) * Sn) * Ln + j;
    bpq[q] = bp + ((size_t)(b0 + q) * (Sn - 1)) * Ln + j;
    coalq[q] = coal + (size_t)(b0 + q) * (Sn / 4);
    fv[q] = fb[q][0];
    cw[q] = 0;
#pragma unroll
    for (int s = 0; s < 4; ++s) pf[q][s] = fb[q][(size_t)(1 + s) * Ln];
  }

  // ---- main loop: t = 1 .. 1016 (254 blocks of 4); prefetch t+4 <= 1020 ----
  for (int tb = 1; tb <= Sn - 11; tb += 4) {
    STEP4(tb + 0, 0, 1, 0, true, tb + 4);
    STEP4(tb + 1, 1, 2, 0, true, tb + 5);
    STEP4(tb + 2, 2, 3, 1, true, tb + 6);
    STEP4(tb + 3, 3, 0, 0, true, tb + 7);
  }
  // After main loop: pf[q][s] = feature[1017 + s].

  // ---- tail A: t = 1017..1020; refill slots 0..2 with features 1021..1023 ----
  STEP4(1017, 0, 1, 0, true, 1021);
  STEP4(1018, 1, 2, 0, true, 1022);
  STEP4(1019, 2, 3, 1, true, 1023);
  STEP4(1020, 3, 0, 0, false, 0);

  // ---- tail B: t = 1021..1023 ----
  STEP4(1021, 0, 1, 0, false, 0);
  STEP4(1022, 1, 2, 0, false, 0);
  STEP4(1023, 2, 3, 1, false, 0);

  // last_tag = first-index argmax of final forward_var, per sequence
  int lt[NSEQ];
#pragma unroll
  for (int q = 0; q < NSEQ; ++q) {
    const float Mf = wave_max64(fv[q]);
    const unsigned long long mk = __ballot(fv[q] == Mf);
    lt[q] = __ffsll((long long)mk) - 1;
  }
  if (j == 0) {
#pragma unroll
    for (int q = 0; q < NSEQ; ++q) last_tag[b0 + q] = lt[q];
  }
}

__global__ __launch_bounds__(256) void crf_backtrace(
    const unsigned char* __restrict__ bp, const unsigned char* __restrict__ coal,
    const int* __restrict__ last_tag, int* __restrict__ out)
{
  const int gid = blockIdx.x * blockDim.x + threadIdx.x;
  if (gid >= Bn * Sn) return;
  const int b = gid >> 10;       // / Sn
  const int t = gid & (Sn - 1);  // % Sn

  const unsigned char* cb = coal + (size_t)b * Sn;
  int tag = -1;
  int u = t;
  // walk forward to the nearest chain break (coalesced k==1 step or sequence end)
  while (u < Sn - 1) {
    const unsigned char c = cb[u + 1];
    if (c != 0xFF) { tag = c; break; }  // path[u] = istar of step u+1
    ++u;
  }
  if (u == Sn - 1) tag = last_tag[b];
  // walk back through non-coalesced steps applying stored backpointers
  const unsigned char* bpb = bp + (size_t)b * (Sn - 1) * Ln;
  for (; u > t; --u) tag = bpb[(size_t)(u - 1) * Ln + tag];
  out[gid] = tag;
}

extern "C" void kernel_launch(void* const* d_in, const int* in_sizes, int n_in,
                              void* d_out, int out_size, void* d_ws, size_t ws_size,
                              hipStream_t stream) {
  const float* feat = (const float*)d_in[0];
  const float* Tm = (const float*)d_in[1];

  // workspace layout: bp | coal | last_tag   (~34 MB total)
  unsigned char* bp = (unsigned char*)d_ws;
  const size_t bp_sz = (size_t)Bn * (Sn - 1) * Ln;  // 33,521,664 (word-aligned)
  unsigned char* coal = bp + bp_sz;
  const size_t coal_sz = (size_t)Bn * Sn;           // 524,288
  int* last_tag = (int*)(coal + coal_sz);

  int* out = (int*)d_out;

  crf_forward4<<<Bn / NSEQ, 64, 0, stream>>>(feat, Tm, bp, (unsigned*)coal, last_tag);
  const int total = Bn * Sn;
  crf_backtrace<<<(total + 255) / 256, 256, 0, stream>>>(bp, coal, last_tag, out);
}

// Round 10
// 408.567 us; speedup vs baseline: 2.6738x; 2.6029x over previous
//
#include <hip/hip_runtime.h>

// Viterbi decode (LinearCRF): features [B,S,L] f32, transitions [L,L] f32 -> best_path [B,S] int32
// B=512, S=1024, L=64. One wave per batch element; lane = tag j.
// Serial 1023-step recurrence. r8/r9 proved: compiler re-serializes any source-level
// ILP (pressure-driven scheduler + in-order issue). Remaining lever: pin emission
// order so mandatory bookkeeping hides inside the ds_read stall shadow.
constexpr int Bn = 512;
constexpr int Sn = 1024;
constexpr int Ln = 64;

// ---- wave64 max reduction via DPP ----
#define DPPMAX(ctrl)                                                          \
  {                                                                           \
    int _xi = __float_as_int(x);                                              \
    int _yi = __builtin_amdgcn_update_dpp(_xi, _xi, ctrl, 0xf, 0xf, false);   \
    x = fmaxf(x, __int_as_float(_yi));                                        \
  }

__device__ __forceinline__ float wave_max64(float x) {
  DPPMAX(0x121)  // row_ror:1
  DPPMAX(0x122)  // row_ror:2
  DPPMAX(0x124)  // row_ror:4
  DPPMAX(0x128)  // row_ror:8
  DPPMAX(0x142)  // row_bcast15
  DPPMAX(0x143)  // row_bcast31 -> lane 63 holds wave max
  return __int_as_float(__builtin_amdgcn_readlane(__float_as_int(x), 63));
}

__device__ __forceinline__ float rdlane(float v, int lane) {
  return __int_as_float(__builtin_amdgcn_readlane(__float_as_int(v), lane));
}

// Bookkeeping block placed in the ds_read stall shadow (identical in both arms).
#define SHADOW_BOOKKEEP(T_, U_, DO_PREF_, PREF_T_, CVEXPR_)                      \
    {                                                                            \
      const unsigned cv__ = (CVEXPR_);                                           \
      cw |= (cv__ << (8 * ((T_) & 3)));                                          \
      if (((T_) & 3) == 3) {                                                     \
        if (j == 0) coalw[(T_) >> 2] = cw;                                       \
        cw = 0;                                                                  \
      }                                                                          \
      if (DO_PREF_) pf[(U_)] = fb[(size_t)(PREF_T_) * Ln];                       \
    }

// One Viterbi step, r7 numerics EXACTLY (verified absmax 0.0), emission-pinned.
// k==1 (81%): sole candidate is the max lane -> fv = featc + (M + T[i0][j]).
// k>=2: 4-candidate strict-> ascending-index tree (+ rare k>4 scan).
#define CRF_STEP(T_, U_, DO_PREF_, PREF_T_)                                      \
  do {                                                                           \
    const float featc_ = pf[(U_)];                                               \
    const float M_ = wave_max64(fv);                                             \
    const float thr_ = M_ - DpE;                                                 \
    const unsigned long long cm_ = __ballot(fv >= thr_);                         \
    const int k_ = __popcll(cm_);                                                \
    const int i0_ = __ffsll((long long)cm_) - 1;                                 \
    float trow0_;                                                                \
    asm volatile("ds_read_b32 %0, %1"                                            \
                 : "=v"(trow0_)                                                  \
                 : "v"(abase + ((unsigned)i0_ << 8)));                           \
    __builtin_amdgcn_sched_barrier(0);                                           \
    if (__builtin_expect(k_ == 1, 1)) {                                          \
      SHADOW_BOOKKEEP(T_, U_, DO_PREF_, PREF_T_, (unsigned)i0_)                  \
      __builtin_amdgcn_sched_barrier(0);                                         \
      asm volatile("s_waitcnt lgkmcnt(0)" ::: "memory");                         \
      __builtin_amdgcn_sched_barrier(0);                                         \
      fv = featc_ + (M_ + trow0_);                                               \
    } else {                                                                     \
      const unsigned long long m1_ = cm_ & (cm_ - 1);                            \
      const unsigned long long m2_ = m1_ & (m1_ - 1);                            \
      const unsigned long long m3_ = m2_ & (m2_ - 1);                            \
      const int i1_ = __ffsll((long long)m1_) - 1;                               \
      const int i2_ = (k_ > 2) ? (__ffsll((long long)m2_) - 1) : i1_;            \
      const int i3_ = (k_ > 3) ? (__ffsll((long long)m3_) - 1) : i1_;            \
      float trow1_, trow2_, trow3_;                                              \
      asm volatile("ds_read_b32 %0, %1"                                          \
                   : "=v"(trow1_) : "v"(abase + ((unsigned)i1_ << 8)));          \
      asm volatile("ds_read_b32 %0, %1"                                          \
                   : "=v"(trow2_) : "v"(abase + ((unsigned)i2_ << 8)));          \
      asm volatile("ds_read_b32 %0, %1"                                          \
                   : "=v"(trow3_) : "v"(abase + ((unsigned)i3_ << 8)));          \
      __builtin_amdgcn_sched_barrier(0);                                         \
      SHADOW_BOOKKEEP(T_, U_, DO_PREF_, PREF_T_, 0xFFu)                          \
      __builtin_amdgcn_sched_barrier(0);                                         \
      asm volatile("s_waitcnt lgkmcnt(0)" ::: "memory");                         \
      __builtin_amdgcn_sched_barrier(0);                                         \
      const float s0_ = rdlane(fv, i0_) + trow0_;                                \
      const float s1_ = rdlane(fv, i1_) + trow1_;                                \
      const float s2_ = rdlane(fv, i2_) + trow2_;                                \
      const float s3_ = rdlane(fv, i3_) + trow3_;                                \
      const bool tkA_ = s1_ > s0_;                                               \
      const float vA_ = tkA_ ? s1_ : s0_;                                        \
      const int xA_ = tkA_ ? i1_ : i0_;                                          \
      const bool tkB_ = s3_ > s2_;                                               \
      const float vB_ = tkB_ ? s3_ : s2_;                                        \
      const int xB_ = tkB_ ? i3_ : i2_;                                          \
      const bool tkF_ = (k_ > 2) && (vB_ > vA_);                                 \
      float best_ = tkF_ ? vB_ : vA_;                                            \
      int bx_ = tkF_ ? xB_ : xA_;                                                \
      if (__builtin_expect(k_ > 4, 0)) {                                         \
        unsigned long long m_ = m3_ & (m3_ - 1);                                 \
        while (m_) {                                                             \
          const int i_ = __ffsll((long long)m_) - 1;                             \
          m_ &= m_ - 1;                                                          \
          const float s_ = rdlane(fv, i_) + sT[i_ * Ln + j];                     \
          const bool tk_ = s_ > best_;                                           \
          best_ = tk_ ? s_ : best_;                                              \
          bx_ = tk_ ? i_ : bx_;                                                  \
        }                                                                        \
      }                                                                          \
      fv = featc_ + best_;                                                       \
      bpb[(size_t)((T_) - 1) * Ln] = (unsigned char)bx_;                         \
    }                                                                            \
  } while (0)

__global__ __launch_bounds__(64) void crf_forward(
    const float* __restrict__ feat,       // [B][S][L]
    const float* __restrict__ Tm,         // [L][L]
    unsigned char* __restrict__ bp,       // [B][S-1][L] backpointers (k>=2 steps only)
    unsigned* __restrict__ coal,          // [B][S/4 words]: per-step istar or 0xFF bytes
    int* __restrict__ last_tag)           // [B]
{
  const int b = blockIdx.x;
  const int j = threadIdx.x;  // tag index 0..63

  __shared__ __align__(16) float sT[Ln * Ln];  // transitions row-major

  // stage T, tracking global span
  float tmx = -1e30f, tmn = 1e30f;
#pragma unroll 8
  for (int i = 0; i < Ln; ++i) {
    const float v = Tm[i * Ln + j];
    sT[i * Ln + j] = v;
    tmx = fmaxf(tmx, v);
    tmn = fminf(tmn, v);
  }
  __syncthreads();
#pragma unroll
  for (int off = 32; off >= 1; off >>= 1) {
    tmx = fmaxf(tmx, __shfl_xor(tmx, off));
    tmn = fminf(tmn, __shfl_xor(tmn, off));
  }
  // fixed margin: Dspan + 0.01 covers all fp rounding (|fv| <= ~6e3 -> 2ulp ~ 1e-3)
  const float DpE = (tmx - tmn) + 0.01f;

  // LDS byte address of this lane's column base (for asm ds_read)
  const unsigned abase = (unsigned)(size_t)(&sT[0]) + ((unsigned)j << 2);

  const float* fb = feat + ((size_t)b * Sn) * Ln + j;
  unsigned char* bpb = bp + ((size_t)b * (Sn - 1)) * Ln + j;
  unsigned* coalw = coal + (size_t)b * (Sn / 4);

  unsigned cw = 0;

  // forward_var = features[b][0][:]; 8-deep software prefetch ring (static indices)
  float fv = fb[0];
  float pf[8];
#pragma unroll
  for (int u = 0; u < 8; ++u) pf[u] = fb[(size_t)(1 + u) * Ln];

  // ---- phase 1: t = 1 .. 1008 (126 blocks of 8); prefetch t+8 <= 1016, no clamp ----
  for (int tb = 1; tb <= Sn - 16; tb += 8) {
#pragma unroll
    for (int u = 0; u < 8; ++u) {
      const int t = tb + u;
      CRF_STEP(t, u, true, t + 8);
    }
  }
  // After phase 1: pf[u] = feature[1009 + u].

  // ---- phase 2: t = 1009 .. 1016; refill pf[0..6] with features 1017..1023 ----
#pragma unroll
  for (int u = 0; u < 8; ++u) {
    const int t = 1009 + u;
    CRF_STEP(t, u, (u < 7), 1017 + u);
  }

  // ---- phase 3: t = 1017 .. 1023 ----
#pragma unroll
  for (int u = 0; u < 7; ++u) {
    const int t = 1017 + u;
    CRF_STEP(t, u, false, 0);
  }

  // last_tag = first-index argmax of final forward_var
  const float Mf = wave_max64(fv);
  const unsigned long long mk = __ballot(fv == Mf);
  if (j == 0) last_tag[b] = __ffsll((long long)mk) - 1;
}

__global__ __launch_bounds__(256) void crf_backtrace(
    const unsigned char* __restrict__ bp, const unsigned char* __restrict__ coal,
    const int* __restrict__ last_tag, int* __restrict__ out)
{
  const int gid = blockIdx.x * blockDim.x + threadIdx.x;
  if (gid >= Bn * Sn) return;
  const int b = gid >> 10;       // / Sn
  const int t = gid & (Sn - 1);  // % Sn

  const unsigned char* cb = coal + (size_t)b * Sn;
  int tag = -1;
  int u = t;
  // walk forward to the nearest chain break (coalesced k==1 step or sequence end)
  while (u < Sn - 1) {
    const unsigned char c = cb[u + 1];
    if (c != 0xFF) { tag = c; break; }  // path[u] = istar of step u+1
    ++u;
  }
  if (u == Sn - 1) tag = last_tag[b];
  // walk back through non-coalesced steps applying stored backpointers
  const unsigned char* bpb = bp + (size_t)b * (Sn - 1) * Ln;
  for (; u > t; --u) tag = bpb[(size_t)(u - 1) * Ln + tag];
  out[gid] = tag;
}

extern "C" void kernel_launch(void* const* d_in, const int* in_sizes, int n_in,
                              void* d_out, int out_size, void* d_ws, size_t ws_size,
                              hipStream_t stream) {
  const float* feat = (const float*)d_in[0];
  const float* Tm = (const float*)d_in[1];

  // workspace layout: bp | coal | last_tag   (~34 MB total)
  unsigned char* bp = (unsigned char*)d_ws;
  const size_t bp_sz = (size_t)Bn * (Sn - 1) * Ln;  // 33,521,664 (word-aligned)
  unsigned char* coal = bp + bp_sz;
  const size_t coal_sz = (size_t)Bn * Sn;           // 524,288
  int* last_tag = (int*)(coal + coal_sz);

  int* out = (int*)d_out;

  crf_forward<<<Bn, 64, 0, stream>>>(feat, Tm, bp, (unsigned*)coal, last_tag);
  const int total = Bn * Sn;
  crf_backtrace<<<(total + 255) / 256, 256, 0, stream>>>(bp, coal, last_tag, out);
}

// Round 11
// 220.411 us; speedup vs baseline: 4.9564x; 1.8537x over previous
//
#include <hip/hip_runtime.h>

// Viterbi decode (LinearCRF): features [B,S,L] f32, transitions [L,L] f32 -> best_path [B,S] int32
// B=512, S=1024, L=64. One wave per batch element; lane = tag j.
// Serial 1023-step recurrence; lone wave pays ~3.5 cyc/instr -> minimize instrs/step.
// FINAL STRUCTURE (r7, 221 us): k==1 fast path 81% (no readlane/select/bp-store),
// k>=2 4-candidate tree 19%. r8/r9 (intra-wave ILP) and r10 (emission pinning)
// all regressed 2x: the compiler's own schedule is the best reachable from HIP.
constexpr int Bn = 512;
constexpr int Sn = 1024;
constexpr int Ln = 64;

// ---- wave64 max reduction via DPP ----
#define DPPMAX(ctrl)                                                          \
  {                                                                           \
    int _xi = __float_as_int(x);                                              \
    int _yi = __builtin_amdgcn_update_dpp(_xi, _xi, ctrl, 0xf, 0xf, false);   \
    x = fmaxf(x, __int_as_float(_yi));                                        \
  }

__device__ __forceinline__ float wave_max64(float x) {
  DPPMAX(0x121)  // row_ror:1
  DPPMAX(0x122)  // row_ror:2
  DPPMAX(0x124)  // row_ror:4
  DPPMAX(0x128)  // row_ror:8
  DPPMAX(0x142)  // row_bcast15
  DPPMAX(0x143)  // row_bcast31 -> lane 63 holds wave max
  return __int_as_float(__builtin_amdgcn_readlane(__float_as_int(x), 63));
}

__device__ __forceinline__ float rdlane(float v, int lane) {
  return __int_as_float(__builtin_amdgcn_readlane(__float_as_int(v), lane));
}

// One Viterbi step. Exact arithmetic: scores rnd(fv_i + T[i][j]); selection strict->
// ascending index == np.argmax first-index rule; candidate set provably supersets
// column winners (margin Dspan + 0.01 >> fp slack).
// k==1 (81%): sole candidate == the max lane (max lane always passes threshold),
//   so fv[i0]==M EXACTLY -> fv = featc + (M + T[i0][j]), cv=i0, no bp store.
// k>=2 (19%): 4-candidate tree. NOTE: i0 is the lowest-INDEX candidate, not the
//   max lane, so its score MUST be rdlane(fv,i0)+t0 (round-6 bug: used M+t0).
#define CRF_STEP(T_, FEATC_)                                                     \
  do {                                                                           \
    const float M_ = wave_max64(fv);                                             \
    const float thr_ = M_ - DpE;                                                 \
    const unsigned long long cm_ = __ballot(fv >= thr_);                         \
    const int k_ = __popcll(cm_);                                                \
    const int i0_ = __ffsll((long long)cm_) - 1;                                 \
    unsigned cv_;                                                                \
    if (__builtin_expect(k_ == 1, 1)) {                                          \
      const float trow_ = sT[i0_ * Ln + j];                                      \
      fv = (FEATC_) + (M_ + trow_);                                              \
      cv_ = (unsigned)i0_;                                                       \
    } else {                                                                     \
      const unsigned long long m1_ = cm_ & (cm_ - 1);                            \
      const unsigned long long m2_ = m1_ & (m1_ - 1);                            \
      const unsigned long long m3_ = m2_ & (m2_ - 1);                            \
      const int i1_ = __ffsll((long long)m1_) - 1;                               \
      const int i2_ = (k_ > 2) ? (__ffsll((long long)m2_) - 1) : i1_;            \
      const int i3_ = (k_ > 3) ? (__ffsll((long long)m3_) - 1) : i1_;            \
      const float t0_ = sT[i0_ * Ln + j];                                        \
      const float t1_ = sT[i1_ * Ln + j];                                        \
      const float t2_ = sT[i2_ * Ln + j];                                        \
      const float t3_ = sT[i3_ * Ln + j];                                        \
      const float s0_ = rdlane(fv, i0_) + t0_;                                   \
      const float s1_ = rdlane(fv, i1_) + t1_;                                   \
      const float s2_ = rdlane(fv, i2_) + t2_;                                   \
      const float s3_ = rdlane(fv, i3_) + t3_;                                   \
      const bool tkA_ = s1_ > s0_;                                               \
      const float vA_ = tkA_ ? s1_ : s0_;                                        \
      const int xA_ = tkA_ ? i1_ : i0_;                                          \
      const bool tkB_ = s3_ > s2_;                                               \
      const float vB_ = tkB_ ? s3_ : s2_;                                        \
      const int xB_ = tkB_ ? i3_ : i2_;                                          \
      const bool okB_ = (k_ > 2);                                                \
      const bool tkF_ = okB_ && (vB_ > vA_);                                     \
      float best_ = tkF_ ? vB_ : vA_;                                            \
      int bx_ = tkF_ ? xB_ : xA_;                                                \
      if (__builtin_expect(k_ > 4, 0)) {                                         \
        unsigned long long m_ = m3_ & (m3_ - 1);                                 \
        while (m_) {                                                             \
          const int i_ = __ffsll((long long)m_) - 1;                             \
          m_ &= m_ - 1;                                                          \
          const float s_ = rdlane(fv, i_) + sT[i_ * Ln + j];                     \
          const bool tk_ = s_ > best_;                                           \
          best_ = tk_ ? s_ : best_;                                              \
          bx_ = tk_ ? i_ : bx_;                                                  \
        }                                                                        \
      }                                                                          \
      fv = (FEATC_) + best_;                                                     \
      bpb[(size_t)((T_) - 1) * Ln] = (unsigned char)bx_;                         \
      cv_ = 0xFFu;                                                               \
    }                                                                            \
    cw = cw | (cv_ << (8 * ((T_) & 3)));                                         \
    if (((T_) & 3) == 3) {                                                       \
      if (j == 0) coalw[(T_) >> 2] = cw;                                         \
      cw = 0;                                                                    \
    }                                                                            \
  } while (0)

__global__ __launch_bounds__(64) void crf_forward(
    const float* __restrict__ feat,       // [B][S][L]
    const float* __restrict__ Tm,         // [L][L]
    unsigned char* __restrict__ bp,       // [B][S-1][L] backpointers (k>=2 steps only)
    unsigned* __restrict__ coal,          // [B][S/4 words]: per-step istar or 0xFF bytes
    int* __restrict__ last_tag)           // [B]
{
  const int b = blockIdx.x;
  const int j = threadIdx.x;  // tag index 0..63

  __shared__ __align__(16) float sT[Ln * Ln];  // transitions row-major

  // stage T, tracking global span
  float tmx = -1e30f, tmn = 1e30f;
#pragma unroll 8
  for (int i = 0; i < Ln; ++i) {
    const float v = Tm[i * Ln + j];
    sT[i * Ln + j] = v;
    tmx = fmaxf(tmx, v);
    tmn = fminf(tmn, v);
  }
  __syncthreads();
#pragma unroll
  for (int off = 32; off >= 1; off >>= 1) {
    tmx = fmaxf(tmx, __shfl_xor(tmx, off));
    tmn = fminf(tmn, __shfl_xor(tmn, off));
  }
  // fixed margin: Dspan + 0.01 covers all fp rounding (|fv| <= ~6e3 -> 2ulp ~ 1e-3)
  const float DpE = (tmx - tmn) + 0.01f;

  const float* fb = feat + ((size_t)b * Sn) * Ln + j;
  unsigned char* bpb = bp + ((size_t)b * (Sn - 1)) * Ln + j;
  unsigned* coalw = coal + (size_t)b * (Sn / 4);

  unsigned cw = 0;

  // forward_var = features[b][0][:]; 8-deep software prefetch ring (static indices)
  float fv = fb[0];
  float pf[8];
#pragma unroll
  for (int u = 0; u < 8; ++u) pf[u] = fb[(size_t)(1 + u) * Ln];

  // ---- phase 1: t = 1 .. 1008 (126 blocks of 8); prefetch t+8 <= 1016, no clamp ----
  for (int tb = 1; tb <= Sn - 16; tb += 8) {
#pragma unroll
    for (int u = 0; u < 8; ++u) {
      const int t = tb + u;
      const float featc = pf[u];
      pf[u] = fb[(size_t)(t + 8) * Ln];
      CRF_STEP(t, featc);
    }
  }
  // After phase 1: pf[u] = feature[1009 + u].

  // ---- phase 2: t = 1009 .. 1016; refill pf[0..6] with features 1017..1023 ----
#pragma unroll
  for (int u = 0; u < 8; ++u) {
    const int t = 1009 + u;
    const float featc = pf[u];
    if (u < 7) pf[u] = fb[(size_t)(1017 + u) * Ln];
    CRF_STEP(t, featc);
  }

  // ---- phase 3: t = 1017 .. 1023 ----
#pragma unroll
  for (int u = 0; u < 7; ++u) {
    const int t = 1017 + u;
    const float featc = pf[u];
    CRF_STEP(t, featc);
  }

  // last_tag = first-index argmax of final forward_var
  const float Mf = wave_max64(fv);
  const unsigned long long mk = __ballot(fv == Mf);
  if (j == 0) last_tag[b] = __ffsll((long long)mk) - 1;
}

__global__ __launch_bounds__(256) void crf_backtrace(
    const unsigned char* __restrict__ bp, const unsigned char* __restrict__ coal,
    const int* __restrict__ last_tag, int* __restrict__ out)
{
  const int gid = blockIdx.x * blockDim.x + threadIdx.x;
  if (gid >= Bn * Sn) return;
  const int b = gid >> 10;       // / Sn
  const int t = gid & (Sn - 1);  // % Sn

  const unsigned char* cb = coal + (size_t)b * Sn;
  int tag = -1;
  int u = t;
  // walk forward to the nearest chain break (coalesced k==1 step or sequence end)
  while (u < Sn - 1) {
    const unsigned char c = cb[u + 1];
    if (c != 0xFF) { tag = c; break; }  // path[u] = istar of step u+1
    ++u;
  }
  if (u == Sn - 1) tag = last_tag[b];
  // walk back through non-coalesced steps applying stored backpointers
  const unsigned char* bpb = bp + (size_t)b * (Sn - 1) * Ln;
  for (; u > t; --u) tag = bpb[(size_t)(u - 1) * Ln + tag];
  out[gid] = tag;
}

extern "C" void kernel_launch(void* const* d_in, const int* in_sizes, int n_in,
                              void* d_out, int out_size, void* d_ws, size_t ws_size,
                              hipStream_t stream) {
  const float* feat = (const float*)d_in[0];
  const float* Tm = (const float*)d_in[1];

  // workspace layout: bp | coal | last_tag   (~34 MB total)
  unsigned char* bp = (unsigned char*)d_ws;
  const size_t bp_sz = (size_t)Bn * (Sn - 1) * Ln;  // 33,521,664 (word-aligned)
  unsigned char* coal = bp + bp_sz;
  const size_t coal_sz = (size_t)Bn * Sn;           // 524,288
  int* last_tag = (int*)(coal + coal_sz);

  int* out = (int*)d_out;

  crf_forward<<<Bn, 64, 0, stream>>>(feat, Tm, bp, (unsigned*)coal, last_tag);
  const int total = Bn * Sn;
  crf_backtrace<<<(total + 255) / 256, 256, 0, stream>>>(bp, coal, last_tag, out);
}